// Round 10
// baseline (331.195 us; speedup 1.0000x reference)
//
#include <hip/hip_runtime.h>
#include <hip/hip_bf16.h>
#include <cstdint>

typedef unsigned short ushortT;
typedef __attribute__((ext_vector_type(8))) short short8;
typedef __attribute__((ext_vector_type(4))) float f32x4;
typedef __attribute__((ext_vector_type(4))) unsigned short us4;

__device__ __forceinline__ ushortT f2bf(float f) {
  union { float f; unsigned u; } v; v.f = f;
  unsigned r = (v.u + 0x7FFFu + ((v.u >> 16) & 1u)) >> 16;
  return (ushortT)r;
}

__device__ __forceinline__ void gl_lds16(const void* g, void* l) {
  __builtin_amdgcn_global_load_lds(
      (__attribute__((address_space(1))) void*)g,
      (__attribute__((address_space(3))) void*)l, 16, 0, 0);
}

// ========= 256x256 tile, 8 waves, 2-phase-per-K-tile, counted vmcnt =========
// C = A @ B^T + bias. BK=32, 4 LDS buffers (128 KiB), 3-tile lookahead.
// Waves: 2M x 4N, wave tile 128x64, acc[8][4] (128 VGPR).
// Per K-tile: 2 quadrant phases (qm=0/1), each:
//   {stage 2 x gl_lds16 (tile kt+3) || 8-or-4 ds_read_b128} -> s_barrier ->
//   setprio(1) 16 MFMA setprio(0) -> s_barrier
// vmcnt(8) once per tile retires tile kt+1's 4 loads (never drains mid-loop).
// mod-4 buffers: stage(kt+3) writes buf (kt-1)&3, whose readers finished at
// tile kt-1's last barrier. Granule swizzle g^=(row>>1)&3: 2-way max (free).
__global__ __launch_bounds__(512, 2) void gemm8p(
    const ushortT* __restrict__ A, const ushortT* __restrict__ B,
    int M, int N, int K,
    float* __restrict__ outF, const float* __restrict__ bias)
{
  __shared__ ushortT smem[4 * 2 * 256 * 32];  // 128 KiB: per buf {A 8192, B 8192} elems
  const int tid = threadIdx.x;
  const int wv = tid >> 6, l = tid & 63;
  const int wm = wv >> 2, wn = wv & 3;

  // XCD swizzle: n fast, m slow (per-XCD ws: A 2MB + B 4MB ~ L2)
  const int bid = blockIdx.x;
  const int xcd = bid & 7, ii = bid >> 3;
  const int n0 = (ii & 7) * 256;
  const int m0 = (xcd * 16 + (ii >> 3)) * 256;
  const int NK = K >> 5;  // 32

  f32x4 acc[8][4] = {};

  const ushortT* Ab = A + (size_t)m0 * (size_t)K;
  const ushortT* Bb = B + (size_t)n0 * (size_t)K;

  const int sr = tid >> 2;               // 0..127
  const int sg = tid & 3;
  const int gsw = sg ^ ((sr >> 1) & 3);  // inverse-swizzled source granule

  auto stageA = [&](int kt, int half) {
    ushortT* base = smem + (kt & 3) * 16384;
    const int r = half * 128 + sr;
    gl_lds16(Ab + (size_t)r * (size_t)K + (size_t)((kt << 5) + (gsw << 3)),
             base + (half * 128 + (wv << 4)) * 32);
  };
  auto stageB = [&](int kt, int half) {
    ushortT* base = smem + (kt & 3) * 16384 + 8192;
    const int r = half * 128 + sr;
    gl_lds16(Bb + (size_t)r * (size_t)K + (size_t)((kt << 5) + (gsw << 3)),
             base + (half * 128 + (wv << 4)) * 32);
  };

  const int fr = l & 15;
  const int colsw = (((l >> 4) ^ ((fr >> 1) & 3)) << 3);

  // prologue: stage tiles 0..2, retire tile 0 (vmcnt(8) leaves tiles 1,2)
  for (int t = 0; t < 3; ++t) { stageA(t, 0); stageA(t, 1); stageB(t, 0); stageB(t, 1); }
  asm volatile("s_waitcnt vmcnt(8)" ::: "memory");
  __builtin_amdgcn_s_barrier();

  for (int kt = 0; kt < NK; ++kt) {
    const ushortT* sAb = smem + (kt & 3) * 16384;
    const ushortT* sBb = sAb + 8192;
    short8 a[4], b[4];

    // ---------------- phase 0: quadrant qm=0 ----------------
    if (kt + 3 < NK) { stageA(kt + 3, 0); stageA(kt + 3, 1); }
#pragma unroll
    for (int fi = 0; fi < 4; ++fi)
      a[fi] = *(const short8*)&sAb[(wm * 128 + fi * 16 + fr) * 32 + colsw];
#pragma unroll
    for (int fj = 0; fj < 4; ++fj)
      b[fj] = *(const short8*)&sBb[(wn * 64 + fj * 16 + fr) * 32 + colsw];
    __builtin_amdgcn_s_barrier();
    __builtin_amdgcn_s_setprio(1);
#pragma unroll
    for (int fi = 0; fi < 4; ++fi)
#pragma unroll
      for (int fj = 0; fj < 4; ++fj)
        acc[fi][fj] = __builtin_amdgcn_mfma_f32_16x16x32_bf16(
            a[fi], b[fj], acc[fi][fj], 0, 0, 0);
    __builtin_amdgcn_s_setprio(0);
    __builtin_amdgcn_s_barrier();

    // ---------------- phase 1: quadrant qm=1 ----------------
    if (kt + 3 < NK) { stageB(kt + 3, 0); stageB(kt + 3, 1); }
#pragma unroll
    for (int fi = 0; fi < 4; ++fi)
      a[fi] = *(const short8*)&sAb[(wm * 128 + 64 + fi * 16 + fr) * 32 + colsw];
    // counted wait: retire tile kt+1's 4 loads (leave kt+2, kt+3 in flight)
    if (kt + 1 < NK) {
      if (kt + 3 < NK)      asm volatile("s_waitcnt vmcnt(8)" ::: "memory");
      else if (kt + 2 < NK) asm volatile("s_waitcnt vmcnt(4)" ::: "memory");
      else                  asm volatile("s_waitcnt vmcnt(0)" ::: "memory");
    }
    __builtin_amdgcn_s_barrier();
    __builtin_amdgcn_s_setprio(1);
#pragma unroll
    for (int fi = 0; fi < 4; ++fi)
#pragma unroll
      for (int fj = 0; fj < 4; ++fj)
        acc[4 + fi][fj] = __builtin_amdgcn_mfma_f32_16x16x32_bf16(
            a[fi], b[fj], acc[4 + fi][fj], 0, 0, 0);
    __builtin_amdgcn_s_setprio(0);
    __builtin_amdgcn_s_barrier();
  }

  // ---- epilogue: 4 x 64-row swaths via LDS, contiguous nt f32x4 stores ----
  const int cc = l & 15, r4 = (l >> 4) * 4;
  float bvv[4];
#pragma unroll
  for (int fj = 0; fj < 4; ++fj) bvv[fj] = bias[n0 + wn * 64 + fj * 16 + cc];

  float* lbuf = (float*)smem;  // 64 rows x 260 stride f32 = 66.6 KiB
#pragma unroll
  for (int s = 0; s < 4; ++s) {
    __syncthreads();
    if (wm == (s >> 1)) {
#pragma unroll
      for (int fi2 = 0; fi2 < 4; ++fi2)
#pragma unroll
        for (int r = 0; r < 4; ++r) {
          const int fi = (s & 1) * 4 + fi2;
          const int row = fi2 * 16 + r4 + r;  // 0..63
#pragma unroll
          for (int fj = 0; fj < 4; ++fj)
            lbuf[row * 260 + wn * 64 + fj * 16 + cc] = acc[fi][fj][r] + bvv[fj];
        }
    }
    __syncthreads();
#pragma unroll
    for (int k2 = 0; k2 < 8; ++k2) {
      const int f = k2 * 512 + tid;       // 4096 f32x4 in 64x256 swath
      const int row = f >> 6, c4 = f & 63;
      f32x4 v = *(const f32x4*)&lbuf[row * 260 + c4 * 4];
      __builtin_nontemporal_store(
          v, (f32x4*)&outF[(size_t)(m0 + s * 64 + row) * (size_t)N + n0 + c4 * 4]);
    }
  }
}

// ---------------- 128x128 tile GEMM, C = A @ B^T, bf16 in, BK=32 -------------
template <int EPI>
__global__ __launch_bounds__(256) void gemm128(
    const ushortT* __restrict__ A, const ushortT* __restrict__ B,
    int M, int N, int K,
    float* __restrict__ outF, ushortT* __restrict__ outBF,
    const float* __restrict__ bias,
    const float* __restrict__ addend,
    float* __restrict__ S2, float* __restrict__ S4,
    ushortT* __restrict__ sdT, int ldT)
{
  __shared__ ushortT sA[2][128 * 32];
  __shared__ ushortT sB[2][128 * 32];
  const int tid = threadIdx.x;
  const int w = tid >> 6, l = tid & 63;
  const int wr = w >> 1, wc = w & 1;
  const int m0 = blockIdx.x * 128, n0 = blockIdx.y * 128;
  const int NK = K >> 5;

  f32x4 acc[4][4] = {};

  auto stage = [&](int buf, int kt) {
    const int k0 = kt << 5;
    const size_t colA = (size_t)(k0 + (l & 3) * 8);
    const int rb = w * 16 + (l >> 2);
#pragma unroll
    for (int c = 0; c < 2; ++c) {
      gl_lds16(A + (size_t)(m0 + c * 64 + rb) * (size_t)K + colA,
               &sA[buf][c * 2048 + w * 512]);
      gl_lds16(B + (size_t)(n0 + c * 64 + rb) * (size_t)K + colA,
               &sB[buf][c * 2048 + w * 512]);
    }
  };

  stage(0, 0);
  __syncthreads();

  for (int kt = 0; kt < NK; ++kt) {
    const int buf = kt & 1;
    if (kt + 1 < NK) stage(buf ^ 1, kt + 1);
    const int ro = (l & 15) * 32 + (l >> 4) * 8;
    short8 a[4], b[4];
#pragma unroll
    for (int f = 0; f < 4; ++f) {
      a[f] = *(const short8*)&sA[buf][(wr * 64 + f * 16) * 32 + ro];
      b[f] = *(const short8*)&sB[buf][(wc * 64 + f * 16) * 32 + ro];
    }
#pragma unroll
    for (int fi = 0; fi < 4; ++fi)
#pragma unroll
      for (int fj = 0; fj < 4; ++fj)
        acc[fi][fj] = __builtin_amdgcn_mfma_f32_16x16x32_bf16(
            a[fi], b[fj], acc[fi][fj], 0, 0, 0);
    __syncthreads();
  }

  const int r4 = (l >> 4) * 4, cc = l & 15;

  if constexpr (EPI == 1) {
#pragma unroll
    for (int fi = 0; fi < 4; ++fi)
#pragma unroll
      for (int r = 0; r < 4; ++r) {
        const size_t gm = (size_t)(m0 + wr * 64 + fi * 16 + r4 + r);
#pragma unroll
        for (int fj = 0; fj < 4; ++fj) {
          const int gn = n0 + wc * 64 + fj * 16 + cc;
          outBF[gm * (size_t)N + gn] = f2bf(acc[fi][fj][r]);
        }
      }
  } else {
    __shared__ ushortT tbuf[128 * 136];
#pragma unroll
    for (int fi = 0; fi < 4; ++fi)
#pragma unroll
      for (int r = 0; r < 4; ++r) {
        const int row = wr * 64 + fi * 16 + r4 + r;
        const size_t gm = (size_t)(m0 + row);
        float rs2 = 0.f, rs4 = 0.f;
#pragma unroll
        for (int fj = 0; fj < 4; ++fj) {
          const int col = wc * 64 + fj * 16 + cc;
          float sd = acc[fi][fj][r] + addend[gm * (size_t)N + n0 + col];
          tbuf[col * 136 + row] = f2bf(sd);
          float s2 = sd * sd;
          rs2 += s2;
          rs4 += s2 * s2;
        }
#pragma unroll
        for (int mk = 1; mk < 16; mk <<= 1) {
          rs2 += __shfl_xor(rs2, mk, 16);
          rs4 += __shfl_xor(rs4, mk, 16);
        }
        if (cc == 0) { atomicAdd(&S2[gm], rs2); atomicAdd(&S4[gm], rs4); }
      }
    __syncthreads();
#pragma unroll
    for (int i = 0; i < 8; ++i) {
      const int er = i * 16 + (tid >> 4);
      const int nc = (tid & 15) * 8;
      short8 v = *(const short8*)&tbuf[er * 136 + nc];
      *(short8*)&sdT[(size_t)(n0 + er) * (size_t)ldT + m0 + nc] = v;
    }
  }
}

// -------- 128x128 split-K GEMM for M = sdT sdT^T: partials, no scaling ------
__global__ __launch_bounds__(256) void mgemm128sk(
    const ushortT* __restrict__ T, int Dm, int K,
    float* __restrict__ pbuf)
{
  __shared__ ushortT sA[2][128 * 32];
  __shared__ ushortT sB[2][128 * 32];
  const int tid = threadIdx.x, w = tid >> 6, l = tid & 63;
  const int wr = w >> 1, wc = w & 1;
  const int i0 = blockIdx.x * 128, j0 = blockIdx.y * 128;
  const int kt0 = blockIdx.z * 64;
  f32x4 acc[4][4] = {};

  auto stage = [&](int buf, int kt) {
    const int k0 = kt << 5;
    const size_t col = (size_t)(k0 + (l & 3) * 8);
    const int rb = w * 16 + (l >> 2);
#pragma unroll
    for (int c = 0; c < 2; ++c) {
      gl_lds16(T + (size_t)(i0 + c * 64 + rb) * (size_t)K + col,
               &sA[buf][c * 2048 + w * 512]);
      gl_lds16(T + (size_t)(j0 + c * 64 + rb) * (size_t)K + col,
               &sB[buf][c * 2048 + w * 512]);
    }
  };

  stage(0, kt0);
  __syncthreads();

  for (int t = 0; t < 64; ++t) {
    const int buf = t & 1;
    if (t + 1 < 64) stage(buf ^ 1, kt0 + t + 1);
    const int ro = (l & 15) * 32 + (l >> 4) * 8;
    short8 a[4], b[4];
#pragma unroll
    for (int f = 0; f < 4; ++f) {
      a[f] = *(const short8*)&sA[buf][(wr * 64 + f * 16) * 32 + ro];
      b[f] = *(const short8*)&sB[buf][(wc * 64 + f * 16) * 32 + ro];
    }
#pragma unroll
    for (int fi = 0; fi < 4; ++fi)
#pragma unroll
      for (int fj = 0; fj < 4; ++fj)
        acc[fi][fj] = __builtin_amdgcn_mfma_f32_16x16x32_bf16(
            a[fi], b[fj], acc[fi][fj], 0, 0, 0);
    __syncthreads();
  }

  const int r4 = (l >> 4) * 4, cc = l & 15;
  float* out = pbuf + ((size_t)blockIdx.z << 20);
#pragma unroll
  for (int fi = 0; fi < 4; ++fi)
#pragma unroll
    for (int r = 0; r < 4; ++r) {
      const int gi = i0 + wr * 64 + fi * 16 + r4 + r;
#pragma unroll
      for (int fj = 0; fj < 4; ++fj) {
        const int gj = j0 + wc * 64 + fj * 16 + cc;
        out[(size_t)gi * (size_t)Dm + gj] = acc[fi][fj][r];
      }
    }
}

__global__ void reduce_grad(const float* __restrict__ pbuf,
                            float* __restrict__ grad, float invN) {
  const int i = blockIdx.x * 256 + threadIdx.x;
  const size_t base = (size_t)i * 4;
  f32x4 s = *(const f32x4*)(pbuf + base) + *(const f32x4*)(pbuf + base + (1u << 20)) +
            *(const f32x4*)(pbuf + base + (2u << 20)) + *(const f32x4*)(pbuf + base + (3u << 20));
  const int row = (int)(base >> 10), c0 = (int)(base & 1023);
  f32x4 o;
#pragma unroll
  for (int j = 0; j < 4; ++j)
    o[j] = 0.5f * (s[j] * invN) - ((row == c0 + j) ? 0.5f : 0.0f);
  *(f32x4*)(grad + base) = o;
}

// ---------------- small utility kernels -------------------------------------
__global__ void zero_f32(float* __restrict__ p, int n) {
  int i = blockIdx.x * blockDim.x + threadIdx.x;
  if (i < n) p[i] = 0.f;
}

__global__ void cvt_f32_bf16(const float* __restrict__ in, ushortT* __restrict__ out,
                             size_t n4) {
  size_t i = (size_t)blockIdx.x * blockDim.x + threadIdx.x;
  const size_t stride = (size_t)gridDim.x * blockDim.x;
  const f32x4* in4 = (const f32x4*)in;
  for (; i < n4; i += stride) {
    f32x4 v = __builtin_nontemporal_load(&in4[i]);
    us4 o = { f2bf(v.x), f2bf(v.y), f2bf(v.z), f2bf(v.w) };
    *(us4*)(out + i * 4) = o;
  }
}

// LDS-tiled coalesced transpose: qT[d][k] = bf16(q[k][d]). grid 8x8, 256 thr.
__global__ __launch_bounds__(256) void transposeQ(const float* __restrict__ q,
                                                  ushortT* __restrict__ qT) {
  __shared__ float t[128][129];
  const int bi = blockIdx.x, bj = blockIdx.y;
  const int tr = threadIdx.x >> 5, tc = threadIdx.x & 31;
#pragma unroll
  for (int i = 0; i < 16; ++i) {
    const int row = i * 8 + tr;
    f32x4 v = *(const f32x4*)&q[(size_t)(bi * 128 + row) * 1024 + bj * 128 + tc * 4];
#pragma unroll
    for (int j = 0; j < 4; ++j) t[row][tc * 4 + j] = v[j];
  }
  __syncthreads();
#pragma unroll
  for (int i = 0; i < 16; ++i) {
    const int dr = i * 8 + tr;
    us4 o = { f2bf(t[tc * 4 + 0][dr]), f2bf(t[tc * 4 + 1][dr]),
              f2bf(t[tc * 4 + 2][dr]), f2bf(t[tc * 4 + 3][dr]) };
    *(us4*)&qT[(size_t)(bj * 128 + dr) * 1024 + bi * 128 + tc * 4] = o;
  }
}

__global__ void make_p(const float* __restrict__ q, ushortT* __restrict__ p) {
  const int g = blockIdx.x * 256 + threadIdx.x;
  const size_t base = (size_t)g * 8;
  const int e = (int)(base >> 10);
  const int d0 = (int)(base & 1023);
  short8 v;
#pragma unroll
  for (int j = 0; j < 8; ++j) {
    float f = q[base + j] - ((e == d0 + j) ? 1.0f : 0.0f);
    v[j] = (short)f2bf(f);
  }
  *(short8*)(p + base) = v;
}

__global__ void gather_rows(const float* __restrict__ x, const int* __restrict__ idx,
                            float* __restrict__ self32, ushortT* __restrict__ selbf) {
  const int bid = blockIdx.x;
  const int b = bid >> 10;
  const int row = idx[bid] & 4095;
  const float4* src = (const float4*)(x + ((size_t)b * 4096 + (size_t)row) * 1024);
  const int t = threadIdx.x;
  float4 v = src[t];
  *(float4*)(self32 + (size_t)bid * 1024 + t * 4) = v;
  us4 o = { f2bf(v.x), f2bf(v.y), f2bf(v.z), f2bf(v.w) };
  *(us4*)(selbf + (size_t)bid * 1024 + t * 4) = o;
}

__global__ void loss_final(const float* __restrict__ S2, const float* __restrict__ S4,
                           float* __restrict__ out) {
  __shared__ double red0[256];
  __shared__ double red1[256];
  const int t = threadIdx.x;
  double ca = 0.0, wa = 0.0;
  for (int i = t; i < 8192; i += 256) {
    double s2 = (double)S2[i], s4 = (double)S4[i];
    ca += s2 * s2 - s4;
    wa += s4 - 2.0 * s2 + 1024.0;
  }
  red0[t] = ca; red1[t] = wa;
  __syncthreads();
  for (int s = 128; s > 0; s >>= 1) {
    if (t < s) { red0[t] += red0[t + s]; red1[t] += red1[t + s]; }
    __syncthreads();
  }
  if (t == 0) {
    const double inv = 1.0 / (8192.0 * 1024.0 * 1024.0);
    out[0] = (float)(red0[0] * inv);
    out[1] = (float)(red1[0] * inv);
  }
}

// ---------------- launch -----------------------------------------------------
extern "C" void kernel_launch(void* const* d_in, const int* in_sizes, int n_in,
                              void* d_out, int out_size, void* d_ws, size_t ws_size,
                              hipStream_t stream) {
  (void)in_sizes; (void)n_in; (void)out_size;
  const float* x = (const float*)d_in[0];
  const float* weight = (const float*)d_in[1];
  const float* bias = (const float*)d_in[2];
  const float* decorr = (const float*)d_in[3];
  const int* sidx = (const int*)d_in[4];

  if (ws_size < 146866176ULL) return;

  char* ws = (char*)d_ws;
  ushortT* xbf     = (ushortT*)(ws);
  ushortT* fusedbf = (ushortT*)(ws + 67108864);
  ushortT* wbf     = (ushortT*)(ws + 71303168);
  ushortT* qT      = (ushortT*)(ws + 75497472);
  ushortT* pbf     = (ushortT*)(ws + 77594624);
  float*   self32  = (float*)  (ws + 79691776);
  ushortT* selbf   = (ushortT*)(ws + 113246208);
  ushortT* sdT     = (ushortT*)(ws + 130023424);
  float*   S2      = (float*)  (ws + 146800640);
  float*   S4      = (float*)  (ws + 146833408);

  float* y = (float*)d_out;
  float* grad = y + 67108864ULL;
  float* losses = grad + 1048576ULL;

  zero_f32<<<dim3(64), dim3(256), 0, stream>>>(S2, 16384);
  cvt_f32_bf16<<<dim3(2048), dim3(256), 0, stream>>>(x, xbf, 8388608);
  cvt_f32_bf16<<<dim3(512), dim3(256), 0, stream>>>(weight, wbf, 524288);
  transposeQ<<<dim3(8, 8), dim3(256), 0, stream>>>(decorr, qT);
  make_p<<<dim3(512), dim3(256), 0, stream>>>(decorr, pbf);
  gather_rows<<<dim3(8192), dim3(256), 0, stream>>>(x, sidx, self32, selbf);

  // fused = W @ Q  ->  bf16
  gemm128<1><<<dim3(16, 8), dim3(256), 0, stream>>>(
      wbf, qT, 2048, 1024, 1024, nullptr, fusedbf, nullptr, nullptr,
      nullptr, nullptr, nullptr, 0);
  // y = x @ fused^T + bias  — 256^2 tile, 2-phase/K-tile, counted vmcnt
  gemm8p<<<dim3(1024), dim3(512), 0, stream>>>(
      xbf, fusedbf, 32768, 2048, 1024, y, bias);
  // sd = sel + sel @ P^T; S2/S4 row sums; sdT transposed bf16
  gemm128<2><<<dim3(64, 8), dim3(256), 0, stream>>>(
      selbf, pbf, 8192, 1024, 1024, nullptr, nullptr, nullptr, self32,
      S2, S4, sdT, 8192);
  // M partials = sdT sdT^T (split-K x4, 128^2 tiles), then reduce
  mgemm128sk<<<dim3(8, 8, 4), dim3(256), 0, stream>>>(sdT, 1024, 8192, self32);
  reduce_grad<<<dim3(1024), dim3(256), 0, stream>>>(self32, grad, 1.0f / 8192.0f);
  loss_final<<<dim3(1), dim3(256), 0, stream>>>(S2, S4, losses);
}